// Round 4
// baseline (184.722 us; speedup 1.0000x reference)
//
#include <hip/hip_runtime.h>
#include <math.h>

#if defined(__has_builtin)
#  if __has_builtin(__builtin_amdgcn_exp2f)
#    define EXP2F(x) __builtin_amdgcn_exp2f(x)
#  endif
#  if __has_builtin(__builtin_amdgcn_rcpf)
#    define RCPF(x) __builtin_amdgcn_rcpf(x)
#  endif
#endif
#ifndef EXP2F
#  define EXP2F(x) exp2f(x)
#endif
#ifndef RCPF
#  define RCPF(x) (1.0f/(x))
#endif

static constexpr int Bn = 16, QN = 512, KN = 512, Hn = 64, DV = 256, DIN = 256;
static constexpr int TQ = 8;
static constexpr int NTASK = Bn * (QN / TQ);             // 1024
static constexpr float TWO_LOG2E = 2.8853900817779268f;  // 2*log2(e)
static constexpr float LOG2E     = 1.4426950408889634f;

typedef __attribute__((ext_vector_type(8))) short short8;  // 8 bf16 (4 VGPRs)
typedef __attribute__((ext_vector_type(4))) float f32x4;

__device__ __forceinline__ short f2bf(float x) {          // RNE fp32->bf16
  unsigned u = __builtin_bit_cast(unsigned, x);
  u += 0x7FFF + ((u >> 16) & 1);
  return (short)(u >> 16);
}
__device__ __forceinline__ float bf2f(short h) {
  return __builtin_bit_cast(float, ((unsigned)(unsigned short)h) << 16);
}

// Projections via MFMA (GEMM: [8192,256] @ [256,64]^T), 3-pass bf16 hi/lo
// split (x = xh + xl; acc += al*bh + ah*bl + ah*bh; dropped al*bl ~ 2^-18).
// Wave: 16 rows x 64 cols, K in 8 chunks of 32. A-frag: A[m=lane&15][k=quad*8+j];
// B-frag: B[k=quad*8+j][n=lane&15] = W[n][k] -> B load = W rows, same pattern as A.
// exp2(2*log2e * acc) fused into the epilogue.
// blocks [0,128): queries -> qe [B,512,64]; [128,256): keys -> ekT [B,64,512].
__global__ __launch_bounds__(256) void proj_mfma(
    const float* __restrict__ queries, const float* __restrict__ keys,
    const float* __restrict__ Wq, const float* __restrict__ Wk,
    float* __restrict__ qe, float* __restrict__ ekT)
{
  int t = threadIdx.x;
  int lane = t & 63, wid = t >> 6;
  bool is_k = blockIdx.x >= 128;
  const float* X = is_k ? keys : queries;
  const float* W = is_k ? Wk : Wq;
  int m0 = (blockIdx.x & 127) * 64 + wid * 16;
  int mr = lane & 15, quad = lane >> 4;
  const float* xp = X + (size_t)(m0 + mr) * DIN + quad * 8;
  const float* wp = W + (size_t)mr * DIN + quad * 8;   // row mr = B col n

  f32x4 acc[4];
  #pragma unroll
  for (int nt = 0; nt < 4; ++nt) acc[nt] = (f32x4){0.f, 0.f, 0.f, 0.f};

  #pragma unroll 2
  for (int kc = 0; kc < 8; ++kc) {
    float4 a0 = *(const float4*)(xp + kc * 32);
    float4 a1 = *(const float4*)(xp + kc * 32 + 4);
    float av[8] = {a0.x, a0.y, a0.z, a0.w, a1.x, a1.y, a1.z, a1.w};
    short8 ah, al;
    #pragma unroll
    for (int j = 0; j < 8; ++j) {
      ah[j] = f2bf(av[j]);
      al[j] = f2bf(av[j] - bf2f(ah[j]));
    }
    #pragma unroll
    for (int nt = 0; nt < 4; ++nt) {
      const float* wc = wp + (size_t)nt * 16 * DIN + kc * 32;
      float4 b0 = *(const float4*)(wc);
      float4 b1 = *(const float4*)(wc + 4);
      float bv[8] = {b0.x, b0.y, b0.z, b0.w, b1.x, b1.y, b1.z, b1.w};
      short8 bh, bl;
      #pragma unroll
      for (int j = 0; j < 8; ++j) {
        bh[j] = f2bf(bv[j]);
        bl[j] = f2bf(bv[j] - bf2f(bh[j]));
      }
      acc[nt] = __builtin_amdgcn_mfma_f32_16x16x32_bf16(al, bh, acc[nt], 0, 0, 0);
      acc[nt] = __builtin_amdgcn_mfma_f32_16x16x32_bf16(ah, bl, acc[nt], 0, 0, 0);
      acc[nt] = __builtin_amdgcn_mfma_f32_16x16x32_bf16(ah, bh, acc[nt], 0, 0, 0);
    }
  }
  // C/D layout: col = lane&15, row = quad*4 + reg  [verified m89]
  #pragma unroll
  for (int nt = 0; nt < 4; ++nt) {
    int col = nt * 16 + mr;
    #pragma unroll
    for (int reg = 0; reg < 4; ++reg) {
      int row = m0 + quad * 4 + reg;
      int b = row >> 9, r = row & (QN - 1);
      float e = EXP2F(acc[nt][reg] * TWO_LOG2E);
      if (!is_k) qe[((size_t)b * QN + r) * Hn + col] = e;
      else       ekT[((size_t)b * Hn + col) * KN + r] = e;
    }
  }
}

// Build LPT task order (batches sorted by L descending -> big tasks first)
// and reset the work-queue counter. 1 block, 256 threads.
__global__ void order_kernel(const int* __restrict__ valid_lens,
                             int* __restrict__ order, int* __restrict__ counter)
{
  int t = threadIdx.x;
  if (t == 0) *counter = 0;
  __shared__ int batch_at[Bn];
  if (t < Bn) {
    int L = valid_lens[t];
    int r = 0;
    #pragma unroll
    for (int b2 = 0; b2 < Bn; ++b2) {
      int L2 = valid_lens[b2];
      if (L2 > L || (L2 == L && b2 < t)) ++r;
    }
    batch_at[r] = t;
  }
  __syncthreads();
  for (int i = t; i < NTASK; i += 256)
    order[i] = batch_at[i >> 6] * 64 + (i & 63);
}

// Persistent fused attention with an LPT work queue (balance across the
// random per-batch L). Task = (b, 8-row q-tile). tanh(q+k)=1-2/(Eq*Ek+1);
// softmax without max-subtraction (|score| <= 3*sum|wv| ~ 20, exp2 safe).
// LDS ~35 KB -> 4 blocks/CU capacity; grid 768 keeps 1024/768 queue slack.
__global__ __launch_bounds__(512) void attn_kernel(
    const float* __restrict__ qe,      // [B,512,64]  exp2(C*q)
    const float* __restrict__ ekT,     // [B,64,512]  exp2(C*k)
    const float* __restrict__ values,  // [B,512,256]
    const int*   __restrict__ valid_lens,
    const float* __restrict__ wv,      // [64]
    const int*   __restrict__ order,
    int*         __restrict__ counter,
    float*       __restrict__ out)     // [B,512,256]
{
  __shared__ __align__(16) float qes2[Hn][8];    // [h][r] 2 KB
  __shared__ __align__(16) float pt[KN][12];     // 24 KB transposed unnorm probs
  __shared__ __align__(16) float pacc[TQ][DV];   // 8 KB PV partial sums
  __shared__ float wsum[8][TQ];
  __shared__ float inv_s[TQ];
  __shared__ int task_s;

  int t = threadIdx.x;
  int lane = t & 63, wave = t >> 6;

  float S = 0.f;                       // sum_h wv[h], task-invariant
  #pragma unroll
  for (int h = 0; h < Hn; ++h) S += wv[h];

  while (true) {
    __syncthreads();                   // previous task fully done with LDS
    if (t == 0) {
      int ti = atomicAdd(counter, 1);
      task_s = (ti < NTASK) ? order[ti] : -1;
    }
    __syncthreads();
    int task = task_s;
    if (task < 0) break;
    int b = task >> 6, q0 = (task & 63) * TQ;
    int L = valid_lens[b];

    {  // stage q-side (b128-broadcast layout [h][r]) + zero pacc
      int h = t >> 3, r = t & 7;
      qes2[h][r] = qe[((size_t)b * QN + q0 + r) * Hn + h];
      #pragma unroll
      for (int i = t; i < TQ * DV; i += 512) ((float*)pacc)[i] = 0.f;
    }
    __syncthreads();

    // ---- scores: thread owns k = t ----
    {
      int k = t;
      float sc[TQ];
      #pragma unroll
      for (int r = 0; r < TQ; ++r) sc[r] = S;
      if (k < L) {
        const float* kbase = ekT + (size_t)b * Hn * KN + k;
        #pragma unroll 2
        for (int h = 0; h < Hn; ++h) {
          float ek = kbase[(size_t)h * KN];          // coalesced
          float4 qa = *(const float4*)&qes2[h][0];   // LDS broadcast
          float4 qb = *(const float4*)&qes2[h][4];
          float w2 = 2.0f * wv[h];
          sc[0] -= w2 * RCPF(qa.x * ek + 1.0f);
          sc[1] -= w2 * RCPF(qa.y * ek + 1.0f);
          sc[2] -= w2 * RCPF(qa.z * ek + 1.0f);
          sc[3] -= w2 * RCPF(qa.w * ek + 1.0f);
          sc[4] -= w2 * RCPF(qb.x * ek + 1.0f);
          sc[5] -= w2 * RCPF(qb.y * ek + 1.0f);
          sc[6] -= w2 * RCPF(qb.z * ek + 1.0f);
          sc[7] -= w2 * RCPF(qb.w * ek + 1.0f);
        }
      }
      float p[TQ];
      #pragma unroll
      for (int r = 0; r < TQ; ++r) p[r] = (k < L) ? EXP2F(sc[r] * LOG2E) : 0.f;
      if (k < L) {
        *(float4*)&pt[k][0] = make_float4(p[0], p[1], p[2], p[3]);
        *(float4*)&pt[k][4] = make_float4(p[4], p[5], p[6], p[7]);
      }
      #pragma unroll
      for (int r = 0; r < TQ; ++r) {   // in-register row sums
        float s = p[r];
        #pragma unroll
        for (int off = 32; off > 0; off >>= 1) s += __shfl_xor(s, off, 64);
        if (lane == r) wsum[wave][r] = s;
      }
    }
    __syncthreads();
    if (t < TQ) {
      float s = 0.f;
      #pragma unroll
      for (int w = 0; w < 8; ++w) s += wsum[w][t];
      inv_s[t] = 1.0f / s;             // read after next barrier
    }

    // ---- PV: thread owns 2 cols x quarter of k; partials via ds_add_f32 ----
    int p2 = t & 127, kq = t >> 7;
    int c = p2 * 2;
    int k0 = (L * kq) >> 2, k1 = (L * (kq + 1)) >> 2;
    float a0[TQ], a1[TQ];
    #pragma unroll
    for (int r = 0; r < TQ; ++r) { a0[r] = 0.f; a1[r] = 0.f; }
    const float* vb = values + (size_t)b * KN * DV + c;
    #pragma unroll 2
    for (int k = k0; k < k1; ++k) {
      float2 v2 = *(const float2*)(vb + (size_t)k * DV);  // coalesced
      float4 pa = *(const float4*)&pt[k][0];              // wave-uniform broadcast
      float4 pb = *(const float4*)&pt[k][4];
      a0[0] += pa.x * v2.x; a1[0] += pa.x * v2.y;
      a0[1] += pa.y * v2.x; a1[1] += pa.y * v2.y;
      a0[2] += pa.z * v2.x; a1[2] += pa.z * v2.y;
      a0[3] += pa.w * v2.x; a1[3] += pa.w * v2.y;
      a0[4] += pb.x * v2.x; a1[4] += pb.x * v2.y;
      a0[5] += pb.y * v2.x; a1[5] += pb.y * v2.y;
      a0[6] += pb.z * v2.x; a1[6] += pb.z * v2.y;
      a0[7] += pb.w * v2.x; a1[7] += pb.w * v2.y;
    }
    if (kq) {
      #pragma unroll
      for (int r = 0; r < TQ; ++r) {
        atomicAdd(&pacc[r][c],     a0[r]);
        atomicAdd(&pacc[r][c + 1], a1[r]);
      }
    }
    __syncthreads();
    if (kq == 0) {
      float* ob = out + ((size_t)b * QN + q0) * DV + c;
      #pragma unroll
      for (int r = 0; r < TQ; ++r) {
        float iv = inv_s[r];
        *(float2*)(ob + (size_t)r * DV) =
            make_float2((a0[r] + pacc[r][c]) * iv, (a1[r] + pacc[r][c + 1]) * iv);
      }
    }
  }
}

extern "C" void kernel_launch(void* const* d_in, const int* in_sizes, int n_in,
                              void* d_out, int out_size, void* d_ws, size_t ws_size,
                              hipStream_t stream) {
  const float* queries    = (const float*)d_in[0];
  const float* keys       = (const float*)d_in[1];
  const float* values     = (const float*)d_in[2];
  const int*   valid_lens = (const int*)d_in[3];
  const float* Wq         = (const float*)d_in[4];
  const float* Wk         = (const float*)d_in[5];
  const float* wv         = (const float*)d_in[6];
  float* out = (float*)d_out;

  char* ws = (char*)d_ws;
  int*   order   = (int*)ws;                         // 4 KB
  int*   counter = (int*)(ws + 4096);                // 4 B
  float* qe      = (float*)(ws + 8192);              // [B,512,64] = 2 MB
  float* ekT     = qe + (size_t)Bn * QN * Hn;        // [B,64,512] = 2 MB

  proj_mfma<<<256, 256, 0, stream>>>(queries, keys, Wq, Wk, qe, ekT);
  order_kernel<<<1, 256, 0, stream>>>(valid_lens, order, counter);
  attn_kernel<<<768, 512, 0, stream>>>(qe, ekT, values, valid_lens, wv,
                                       order, counter, out);
}

// Round 5
// 171.109 us; speedup vs baseline: 1.0796x; 1.0796x over previous
//
#include <hip/hip_runtime.h>
#include <math.h>

#if defined(__has_builtin)
#  if __has_builtin(__builtin_amdgcn_exp2f)
#    define EXP2F(x) __builtin_amdgcn_exp2f(x)
#  endif
#  if __has_builtin(__builtin_amdgcn_rcpf)
#    define RCPF(x) __builtin_amdgcn_rcpf(x)
#  endif
#endif
#ifndef EXP2F
#  define EXP2F(x) exp2f(x)
#endif
#ifndef RCPF
#  define RCPF(x) (1.0f/(x))
#endif

static constexpr int Bn = 16, QN = 512, KN = 512, Hn = 64, DV = 256, DIN = 256;
static constexpr int TQ = 8;
static constexpr float TWO_LOG2E = 2.8853900817779268f;  // 2*log2(e)
static constexpr float LOG2E     = 1.4426950408889634f;

typedef __attribute__((ext_vector_type(8))) short short8;  // 8 bf16 (4 VGPRs)
typedef __attribute__((ext_vector_type(4))) float f32x4;

__device__ __forceinline__ short f2bf(float x) {          // RNE fp32->bf16
  unsigned u = __builtin_bit_cast(unsigned, x);
  u += 0x7FFF + ((u >> 16) & 1);
  return (short)(u >> 16);
}
__device__ __forceinline__ float bf2f(short h) {
  return __builtin_bit_cast(float, ((unsigned)(unsigned short)h) << 16);
}

// One-time W conversion: Wq,Wk [64][256] f32 -> bf16 hi/lo arrays (row-major,
// so a B-fragment load is 8 consecutive ushorts = one dwordx4). Removes the
// per-block redundant conversion that made R4's proj latency-bound.
__global__ __launch_bounds__(256) void prep_kernel(
    const float* __restrict__ Wq, const float* __restrict__ Wk,
    ushort* __restrict__ wqh, ushort* __restrict__ wql,
    ushort* __restrict__ wkh, ushort* __restrict__ wkl)
{
  int i = blockIdx.x * 256 + threadIdx.x;     // grid 64 blocks -> 16384 = 64*256
  float xq = Wq[i];
  short hq = f2bf(xq);
  wqh[i] = (ushort)hq; wql[i] = (ushort)f2bf(xq - bf2f(hq));
  float xk = Wk[i];
  short hk = f2bf(xk);
  wkh[i] = (ushort)hk; wkl[i] = (ushort)f2bf(xk - bf2f(hk));
}

// Projections via MFMA, 3-pass bf16 hi/lo (x=xh+xl; al*bh + ah*bl + ah*bh).
// 1024 row-tiles (16 rows each; q rows 0..8191, k rows 8192..16383).
// Each wave: one 16-row tile x 32 cols (col-half split) -> 2048 wave-units,
// 512 blocks x 4 waves = 2 blocks/CU (R4 had 1 block/CU -> latency-bound).
// B side loads pre-converted bf16 (zero conversion VALU). exp2 fused.
__global__ __launch_bounds__(256) void proj_mfma(
    const float* __restrict__ queries, const float* __restrict__ keys,
    const ushort* __restrict__ wqh, const ushort* __restrict__ wql,
    const ushort* __restrict__ wkh, const ushort* __restrict__ wkl,
    float* __restrict__ qe, float* __restrict__ ekT)
{
  int t = threadIdx.x;
  int lane = t & 63, wid = t >> 6;
  int tile = blockIdx.x * 2 + (wid >> 1);        // 0..1023
  int nhalf = wid & 1;                           // which 32-col half
  bool is_k = tile >= 512;
  int trow = (tile & 511) * 16;                  // row within its matrix
  const float*  X  = is_k ? keys : queries;
  const ushort* Wh = is_k ? wkh : wqh;
  const ushort* Wl = is_k ? wkl : wql;
  int mr = lane & 15, quad = lane >> 4;
  const float* xp = X + (size_t)(trow + mr) * DIN + quad * 8;
  int coln = nhalf * 32 + mr;                    // B col n for nt=0
  const ushort* whp = Wh + (size_t)coln * DIN + quad * 8;
  const ushort* wlp = Wl + (size_t)coln * DIN + quad * 8;

  f32x4 acc[2];
  acc[0] = (f32x4){0.f, 0.f, 0.f, 0.f};
  acc[1] = (f32x4){0.f, 0.f, 0.f, 0.f};

  #pragma unroll
  for (int kc = 0; kc < 8; ++kc) {
    float4 a0 = *(const float4*)(xp + kc * 32);
    float4 a1 = *(const float4*)(xp + kc * 32 + 4);
    float av[8] = {a0.x, a0.y, a0.z, a0.w, a1.x, a1.y, a1.z, a1.w};
    short8 ah, al;
    #pragma unroll
    for (int j = 0; j < 8; ++j) {
      ah[j] = f2bf(av[j]);
      al[j] = f2bf(av[j] - bf2f(ah[j]));
    }
    #pragma unroll
    for (int nt = 0; nt < 2; ++nt) {
      short8 bh = *(const short8*)(whp + (size_t)nt * 16 * DIN + kc * 32);
      short8 bl = *(const short8*)(wlp + (size_t)nt * 16 * DIN + kc * 32);
      acc[nt] = __builtin_amdgcn_mfma_f32_16x16x32_bf16(al, bh, acc[nt], 0, 0, 0);
      acc[nt] = __builtin_amdgcn_mfma_f32_16x16x32_bf16(ah, bl, acc[nt], 0, 0, 0);
      acc[nt] = __builtin_amdgcn_mfma_f32_16x16x32_bf16(ah, bh, acc[nt], 0, 0, 0);
    }
  }
  // C/D: col = lane&15, row = quad*4 + reg  [verified m89; R4 passed]
  #pragma unroll
  for (int nt = 0; nt < 2; ++nt) {
    int col = nhalf * 32 + nt * 16 + mr;
    #pragma unroll
    for (int reg = 0; reg < 4; ++reg) {
      int row = trow + quad * 4 + reg;
      int b = row >> 9, r = row & (QN - 1);
      float e = EXP2F(acc[nt][reg] * TWO_LOG2E);
      if (!is_k) qe[((size_t)b * QN + r) * Hn + col] = e;
      else       ekT[((size_t)b * Hn + col) * KN + r] = e;
    }
  }
}

// Fused attention, 256-thread blocks (4 waves), TQ=8 q-rows per block.
// tanh(q+k) = 1 - 2/(Eq*Ek+1): fma + rcp + fma per element (exp2 in proj).
// Scores bounded (|s| <= sum|wv| ~ 7): softmax without max-subtraction.
// Thread covers k = t and t+256 (avg lane idle 37% vs 50% at 512 thr).
// LDS ~18.6 KB -> all 4 blocks/CU co-resident; phases of different blocks
// overlap (score = rcp pipe, PV = fma pipe). No pacc: thread owns one
// output column over the FULL k range.
__global__ __launch_bounds__(256, 4) void attn_kernel(
    const float* __restrict__ qe,      // [B,512,64]  exp2(C*q)
    const float* __restrict__ ekT,     // [B,64,512]  exp2(C*k)
    const float* __restrict__ values,  // [B,512,256]
    const int*   __restrict__ valid_lens,
    const float* __restrict__ wv,      // [64]
    float* __restrict__ out)           // [B,512,256]
{
  __shared__ __align__(16) float qes2[Hn][TQ];   // [h][r] 2 KB
  __shared__ __align__(16) float pt[KN][TQ];     // 16 KB transposed unnorm probs
  __shared__ float wsum[4][TQ];
  __shared__ float inv_s[TQ];

  int t = threadIdx.x;
  int b = blockIdx.x >> 6;                 // CU's 4 blocks {c,c+256,..} span 4 batches
  int q0 = (blockIdx.x & 63) * TQ;
  int L = valid_lens[b];                   // uniform per batch; masked k skipped
  int lane = t & 63, wave = t >> 6;

  {  // stage q-side in [h][r] broadcast layout
    int i0 = t, i1 = t + 256;
    qes2[i0 >> 3][i0 & 7] = qe[((size_t)b * QN + q0 + (i0 & 7)) * Hn + (i0 >> 3)];
    qes2[i1 >> 3][i1 & 7] = qe[((size_t)b * QN + q0 + (i1 & 7)) * Hn + (i1 >> 3)];
  }
  __syncthreads();

  float S = 0.f;                           // sum_h wv[h], hoisted
  #pragma unroll
  for (int h = 0; h < Hn; ++h) S += wv[h];

  // ---- scores: thread owns k = t and t+256 ----
  float rowsum[TQ];
  #pragma unroll
  for (int r = 0; r < TQ; ++r) rowsum[r] = 0.f;
  #pragma unroll
  for (int j = 0; j < 2; ++j) {
    int k = t + j * 256;
    if (k < L) {                           // uniform skip of j=1 when L<=256
      float sc[TQ];
      #pragma unroll
      for (int r = 0; r < TQ; ++r) sc[r] = S;
      const float* kbase = ekT + (size_t)b * Hn * KN + k;
      #pragma unroll 2
      for (int h = 0; h < Hn; ++h) {
        float ek = kbase[(size_t)h * KN];          // coalesced
        float4 qa = *(const float4*)&qes2[h][0];   // LDS broadcast
        float4 qb = *(const float4*)&qes2[h][4];
        float w2 = 2.0f * wv[h];
        sc[0] -= w2 * RCPF(qa.x * ek + 1.0f);
        sc[1] -= w2 * RCPF(qa.y * ek + 1.0f);
        sc[2] -= w2 * RCPF(qa.z * ek + 1.0f);
        sc[3] -= w2 * RCPF(qa.w * ek + 1.0f);
        sc[4] -= w2 * RCPF(qb.x * ek + 1.0f);
        sc[5] -= w2 * RCPF(qb.y * ek + 1.0f);
        sc[6] -= w2 * RCPF(qb.z * ek + 1.0f);
        sc[7] -= w2 * RCPF(qb.w * ek + 1.0f);
      }
      float p[TQ];
      #pragma unroll
      for (int r = 0; r < TQ; ++r) { p[r] = EXP2F(sc[r] * LOG2E); rowsum[r] += p[r]; }
      *(float4*)&pt[k][0] = make_float4(p[0], p[1], p[2], p[3]);
      *(float4*)&pt[k][4] = make_float4(p[4], p[5], p[6], p[7]);
    }
  }
  #pragma unroll
  for (int r = 0; r < TQ; ++r) {           // in-register row sums
    float s = rowsum[r];
    #pragma unroll
    for (int off = 32; off > 0; off >>= 1) s += __shfl_xor(s, off, 64);
    if (lane == r) wsum[wave][r] = s;
  }
  __syncthreads();
  if (t < TQ) {
    float s = wsum[0][t] + wsum[1][t] + wsum[2][t] + wsum[3][t];
    inv_s[t] = 1.0f / s;
  }
  __syncthreads();

  // ---- PV: thread owns col t, full k range ----
  float acc[TQ];
  #pragma unroll
  for (int r = 0; r < TQ; ++r) acc[r] = 0.f;
  const float* vb = values + (size_t)b * KN * DV + t;
  #pragma unroll 2
  for (int k = 0; k < L; ++k) {
    float val = vb[(size_t)k * DV];          // coalesced
    float4 pa = *(const float4*)&pt[k][0];   // broadcast (same addr all lanes)
    float4 pb = *(const float4*)&pt[k][4];
    acc[0] += pa.x * val; acc[1] += pa.y * val;
    acc[2] += pa.z * val; acc[3] += pa.w * val;
    acc[4] += pb.x * val; acc[5] += pb.y * val;
    acc[6] += pb.z * val; acc[7] += pb.w * val;
  }
  float* ob = out + ((size_t)b * QN + q0) * DV + t;
  #pragma unroll
  for (int r = 0; r < TQ; ++r) ob[(size_t)r * DV] = acc[r] * inv_s[r];
}

extern "C" void kernel_launch(void* const* d_in, const int* in_sizes, int n_in,
                              void* d_out, int out_size, void* d_ws, size_t ws_size,
                              hipStream_t stream) {
  const float* queries    = (const float*)d_in[0];
  const float* keys       = (const float*)d_in[1];
  const float* values     = (const float*)d_in[2];
  const int*   valid_lens = (const int*)d_in[3];
  const float* Wq         = (const float*)d_in[4];
  const float* Wk         = (const float*)d_in[5];
  const float* wv         = (const float*)d_in[6];
  float* out = (float*)d_out;

  char* ws = (char*)d_ws;
  float*  qe  = (float*)ws;                          // [B,512,64] = 2 MB
  float*  ekT = qe + (size_t)Bn * QN * Hn;           // [B,64,512] = 2 MB
  ushort* wqh = (ushort*)(ekT + (size_t)Bn * Hn * KN);
  ushort* wql = wqh + Hn * DIN;                      // 4 x 32 KB
  ushort* wkh = wql + Hn * DIN;
  ushort* wkl = wkh + Hn * DIN;

  prep_kernel<<<64, 256, 0, stream>>>(Wq, Wk, wqh, wql, wkh, wkl);
  proj_mfma<<<512, 256, 0, stream>>>(queries, keys, wqh, wql, wkh, wkl, qe, ekT);
  attn_kernel<<<Bn * (QN / TQ), 256, 0, stream>>>(qe, ekT, values,
                                                  valid_lens, wv, out);
}

// Round 6
// 149.622 us; speedup vs baseline: 1.2346x; 1.1436x over previous
//
#include <hip/hip_runtime.h>
#include <math.h>

#if defined(__has_builtin)
#  if __has_builtin(__builtin_amdgcn_exp2f)
#    define EXP2F(x) __builtin_amdgcn_exp2f(x)
#  endif
#  if __has_builtin(__builtin_amdgcn_rcpf)
#    define RCPF(x) __builtin_amdgcn_rcpf(x)
#  endif
#endif
#ifndef EXP2F
#  define EXP2F(x) exp2f(x)
#endif
#ifndef RCPF
#  define RCPF(x) (1.0f/(x))
#endif

static constexpr int Bn = 16, QN = 512, KN = 512, Hn = 64, DV = 256, DIN = 256;
static constexpr int TQ = 8;
static constexpr int NTASK = Bn * (QN / TQ);             // 1024
static constexpr float TWO_LOG2E = 2.8853900817779268f;  // 2*log2(e)
static constexpr float LOG2E     = 1.4426950408889634f;

// Pack W into pair-interleaved transposed layout Wp[k2][h][2] so proj's
// per-lane W read is one coalesced float2 (lane = h consecutive).
__global__ __launch_bounds__(256) void prep_kernel(
    const float* __restrict__ Wq, const float* __restrict__ Wk,
    float* __restrict__ wpq, float* __restrict__ wpk)
{
  int i = blockIdx.x * 256 + threadIdx.x;   // 0..8191 = 128 k2 x 64 h
  int k2 = i >> 6, h = i & 63;
  wpq[i * 2 + 0] = Wq[h * DIN + 2 * k2];
  wpq[i * 2 + 1] = Wq[h * DIN + 2 * k2 + 1];
  wpk[i * 2 + 0] = Wk[h * DIN + 2 * k2];
  wpk[i * 2 + 1] = Wk[h * DIN + 2 * k2 + 1];
}

// Projections, fp32 VALU, occupancy-first: 1024 blocks x 256 thr
// (4 blocks/CU; prior rounds' proj ran at <=2 blocks/CU and was
// latency-bound at 50-90us vs a 3.4us issue floor).
// Wave = 4 rows x 64 cols. X row reads are wave-uniform -> s_load
// broadcasts (SGPR fma operand); W reads are coalesced float2 from Wp.
// exp2(2*log2e*acc) fused. k-side transposed through LDS so ekT stores
// are coalesced along k (direct stores would be a 64-line scatter).
__global__ __launch_bounds__(256) void proj_kernel(
    const float* __restrict__ queries, const float* __restrict__ keys,
    const float* __restrict__ wpq, const float* __restrict__ wpk,
    float* __restrict__ qe, float* __restrict__ ekT)
{
  __shared__ float tr[Hn][17];                 // 4.3 KB transpose staging
  int t = threadIdx.x;
  int h = t & 63;
  int w4 = __builtin_amdgcn_readfirstlane(t >> 6);   // wave id 0..3
  bool is_k = blockIdx.x >= 512;
  int tile = blockIdx.x & 511;                 // 512 tiles x 16 rows per matrix
  const float* X  = is_k ? keys : queries;
  const float* Wp = is_k ? wpk : wpq;
  int row0 = tile * 16 + w4 * 4;               // wave's 4 rows
  const float* x0 = X + (size_t)row0 * DIN;

  float a0 = 0.f, a1 = 0.f, a2 = 0.f, a3 = 0.f;
  #pragma unroll 4
  for (int c = 0; c < 32; ++c) {               // 8 k per chunk
    // W: 4 coalesced float2 (lane = h)
    float2 wa = *(const float2*)(Wp + ((size_t)(4 * c + 0) * Hn + h) * 2);
    float2 wb = *(const float2*)(Wp + ((size_t)(4 * c + 1) * Hn + h) * 2);
    float2 wc = *(const float2*)(Wp + ((size_t)(4 * c + 2) * Hn + h) * 2);
    float2 wd = *(const float2*)(Wp + ((size_t)(4 * c + 3) * Hn + h) * 2);
    #pragma unroll
    for (int j = 0; j < 4; ++j) {
      // wave-uniform -> s_load_dwordx4 pairs (merge to dwordx8)
      float4 xa = *(const float4*)(x0 + (size_t)j * DIN + c * 8);
      float4 xb = *(const float4*)(x0 + (size_t)j * DIN + c * 8 + 4);
      float s = xa.x * wa.x + xa.y * wa.y + xa.z * wb.x + xa.w * wb.y
              + xb.x * wc.x + xb.y * wc.y + xb.z * wd.x + xb.w * wd.y;
      if (j == 0) a0 += s; else if (j == 1) a1 += s;
      else if (j == 2) a2 += s; else a3 += s;
    }
  }
  float e[4] = {EXP2F(a0 * TWO_LOG2E), EXP2F(a1 * TWO_LOG2E),
                EXP2F(a2 * TWO_LOG2E), EXP2F(a3 * TWO_LOG2E)};
  if (!is_k) {
    // qe is [8192][64]: lanes = consecutive h -> coalesced
    #pragma unroll
    for (int j = 0; j < 4; ++j)
      qe[(size_t)(row0 + j) * Hn + h] = e[j];
  } else {
    #pragma unroll
    for (int j = 0; j < 4; ++j) tr[h][w4 * 4 + j] = e[j];   // 2-way banks: free
    __syncthreads();
    int h2 = t >> 2, kk = t & 3;
    int krow = tile * 16;                       // k-rows this block covers
    int b = krow >> 9, k0 = (krow & (KN - 1)) + kk * 4;
    float4 v = make_float4(tr[h2][kk * 4], tr[h2][kk * 4 + 1],
                           tr[h2][kk * 4 + 2], tr[h2][kk * 4 + 3]);
    *(float4*)(ekT + ((size_t)b * Hn + h2) * KN + k0) = v;  // 16 lines/instr
  }
}

// Static LPT schedule: order[] = (b,qtile) tasks, batches sorted by L
// descending. attn block i takes order[i]; HW dispatch (~in order, next
// block when a CU slot frees) realizes greedy longest-first balancing.
// Dispatch order is a perf heuristic only - any order is correct.
__global__ void order_kernel(const int* __restrict__ valid_lens,
                             int* __restrict__ order)
{
  int t = threadIdx.x;
  __shared__ int batch_at[Bn];
  if (t < Bn) {
    int L = valid_lens[t];
    int r = 0;
    #pragma unroll
    for (int b2 = 0; b2 < Bn; ++b2) {
      int L2 = valid_lens[b2];
      if (L2 > L || (L2 == L && b2 < t)) ++r;
    }
    batch_at[r] = t;
  }
  __syncthreads();
  for (int i = t; i < NTASK; i += 256)
    order[i] = batch_at[i >> 6] * 64 + (i & 63);
}

// Fused attention (R3 shape: 512 thr, thread owns k = t in score).
// tanh(q+k) = 1 - 2/(Eq*Ek+1): fma + rcp + fma per element (exp2 in proj).
// Scores bounded (|s| <= sum|wv| ~ 7): softmax without max-subtraction.
// Fixes vs R3: (a) LDS 48.5->34.4 KB (2-way PV split) -> 4 blocks/CU = 32
// waves; (b) score loop grouped by 8 h with loads issued first (8 ekT
// loads in flight vs 2); (c) LPT task order.
__global__ __launch_bounds__(512) void attn_kernel(
    const float* __restrict__ qe,      // [B,512,64]  exp2(C*q)
    const float* __restrict__ ekT,     // [B,64,512]  exp2(C*k)
    const float* __restrict__ values,  // [B,512,256]
    const int*   __restrict__ valid_lens,
    const float* __restrict__ wv,      // [64]
    const int*   __restrict__ order,
    float* __restrict__ out)           // [B,512,256]
{
  __shared__ __align__(16) float qes2[Hn][TQ];   // 2 KB   [h][r] broadcast layout
  __shared__ __align__(16) float pt[KN][12];     // 24 KB  stride 12: 0 conflicts (R3)
  __shared__ __align__(16) float pacc[TQ][DV];   // 8 KB   upper-half PV partials
  __shared__ float wsum[8][TQ];
  __shared__ float inv_s[TQ];

  int t = threadIdx.x;
  int task = order[blockIdx.x];
  int b = task >> 6;
  int q0 = (task & 63) * TQ;
  int L = valid_lens[b];                   // uniform per batch; masked k skipped
  int lane = t & 63, wave = t >> 6;

  qes2[t >> 3][t & 7] = qe[(size_t)(b * QN + q0 + (t & 7)) * Hn + (t >> 3)];
  __syncthreads();

  float S = 0.f;                           // sum_h wv[h], hoisted
  #pragma unroll
  for (int h = 0; h < Hn; ++h) S += wv[h];

  // ---- scores: thread owns k = t ----
  float rowsum[TQ];
  {
    int k = t;
    float p[TQ];
    if (k < L) {
      float sc[TQ];
      #pragma unroll
      for (int r = 0; r < TQ; ++r) sc[r] = S;
      const float* kb = ekT + (size_t)b * Hn * KN + k;
      for (int h0 = 0; h0 < Hn; h0 += 8) {
        float ekv[8];
        #pragma unroll
        for (int j = 0; j < 8; ++j)                    // 8 loads in flight
          ekv[j] = kb[(size_t)(h0 + j) * KN];
        #pragma unroll
        for (int j = 0; j < 8; ++j) {
          int h = h0 + j;
          float w2 = 2.0f * wv[h];                     // s_load, cached
          float4 qa = *(const float4*)&qes2[h][0];     // LDS broadcast
          float4 qb = *(const float4*)&qes2[h][4];
          float ek = ekv[j];
          sc[0] -= w2 * RCPF(qa.x * ek + 1.0f);
          sc[1] -= w2 * RCPF(qa.y * ek + 1.0f);
          sc[2] -= w2 * RCPF(qa.z * ek + 1.0f);
          sc[3] -= w2 * RCPF(qa.w * ek + 1.0f);
          sc[4] -= w2 * RCPF(qb.x * ek + 1.0f);
          sc[5] -= w2 * RCPF(qb.y * ek + 1.0f);
          sc[6] -= w2 * RCPF(qb.z * ek + 1.0f);
          sc[7] -= w2 * RCPF(qb.w * ek + 1.0f);
        }
      }
      #pragma unroll
      for (int r = 0; r < TQ; ++r) p[r] = EXP2F(sc[r] * LOG2E);
      *(float4*)&pt[k][0] = make_float4(p[0], p[1], p[2], p[3]);
      *(float4*)&pt[k][4] = make_float4(p[4], p[5], p[6], p[7]);
    } else {
      #pragma unroll
      for (int r = 0; r < TQ; ++r) p[r] = 0.f;
    }
    #pragma unroll
    for (int r = 0; r < TQ; ++r) {         // in-register row sums
      float s = p[r];
      #pragma unroll
      for (int off = 32; off > 0; off >>= 1) s += __shfl_xor(s, off, 64);
      rowsum[r] = s;
    }
    if (lane < TQ) wsum[wave][lane] = rowsum[lane];
  }
  __syncthreads();
  if (t < TQ) {
    float s = 0.f;
    #pragma unroll
    for (int w = 0; w < 8; ++w) s += wsum[w][t];
    inv_s[t] = 1.0f / s;                   // read after the pacc barrier
  }

  // ---- PV: thread owns col c = t&255, half of k (t>>8) ----
  int c = t & (DV - 1), half = t >> 8;
  int mid = L >> 1;
  int k0 = half ? mid : 0;
  int k1 = half ? L : mid;
  float acc[TQ];
  #pragma unroll
  for (int r = 0; r < TQ; ++r) acc[r] = 0.f;
  const float* vb = values + (size_t)b * KN * DV + c;
  #pragma unroll 4
  for (int k = k0; k < k1; ++k) {
    float val = vb[(size_t)k * DV];          // coalesced (wave = 64 consecutive c)
    float4 pa = *(const float4*)&pt[k][0];   // same addr all lanes: broadcast
    float4 pb = *(const float4*)&pt[k][4];
    acc[0] += pa.x * val; acc[1] += pa.y * val;
    acc[2] += pa.z * val; acc[3] += pa.w * val;
    acc[4] += pb.x * val; acc[5] += pb.y * val;
    acc[6] += pb.z * val; acc[7] += pb.w * val;
  }
  if (half) {
    #pragma unroll
    for (int r = 0; r < TQ; ++r) pacc[r][c] = acc[r];
  }
  __syncthreads();
  if (!half) {
    float* ob = out + (size_t)(b * QN + q0) * DV + c;
    #pragma unroll
    for (int r = 0; r < TQ; ++r)
      ob[(size_t)r * DV] = (acc[r] + pacc[r][c]) * inv_s[r];
  }
}

extern "C" void kernel_launch(void* const* d_in, const int* in_sizes, int n_in,
                              void* d_out, int out_size, void* d_ws, size_t ws_size,
                              hipStream_t stream) {
  const float* queries    = (const float*)d_in[0];
  const float* keys       = (const float*)d_in[1];
  const float* values     = (const float*)d_in[2];
  const int*   valid_lens = (const int*)d_in[3];
  const float* Wq         = (const float*)d_in[4];
  const float* Wk         = (const float*)d_in[5];
  const float* wv         = (const float*)d_in[6];
  float* out = (float*)d_out;

  char* ws = (char*)d_ws;
  float* qe  = (float*)ws;                           // [8192][64] = 2 MB
  float* ekT = qe + (size_t)Bn * QN * Hn;            // [B,64,512] = 2 MB
  float* wpq = ekT + (size_t)Bn * Hn * KN;           // 64 KB
  float* wpk = wpq + Hn * DIN;                       // 64 KB
  int* order = (int*)(wpk + Hn * DIN);               // 4 KB

  prep_kernel<<<32, 256, 0, stream>>>(Wq, Wk, wpq, wpk);
  order_kernel<<<1, 256, 0, stream>>>(valid_lens, order);
  proj_kernel<<<1024, 256, 0, stream>>>(queries, keys, wpq, wpk, qe, ekT);
  attn_kernel<<<NTASK, 512, 0, stream>>>(qe, ekT, values, valid_lens, wv,
                                         order, out);
}